// Round 6
// baseline (669717.334 us; speedup 1.0000x reference)
//
#include <hip/hip_runtime.h>
#include <stdint.h>

// ---------------------------------------------------------------------------
// FastWaveNet autoregressive sampler v8 — persistent pipeline with
// self-validating stamped 64-bit records.
// v8: ATOMIC-L2 fast path + interleaved arbitration + hit-count adaptivity.
//   Producer publishes each record twice (disjoint addresses):
//     fast slot: u64 atomic_exchange, workgroup scope -> executes at the
//                producer XCD's L2 (atomics are never served by L1).
//     slow slot: v2 agent-scope store (the proven coherent path).
//   Consumer wait loop interleaves {4 fast polls ; 1 verbatim v2 slow poll}
//   with no timeouts (v6's 3us fast window could never open against the
//   ring's ~100us wait; v7 showed the store+sc0 mechanism never hits).
//   Fast poll = atomic_fetch_add of an OPAQUE runtime zero (RMW executes at
//   the consumer XCD's L2 -> same L2 as producer on co-located legs; opaque
//   operand blocks idempotent-RMW->load demotion). Cross-XCD legs see a
//   stale line forever (their own L2 pins it dirty) and are served by the
//   slow poll at v2 latency -> correct under ANY placement.
//   Adaptivity by STEP COUNT, not time: consumers with <8 fast hits in the
//   first 48 steps disable fast polling (bounds all-miss overhead to ~1ms).
//   Single-word FIDX is fast-polled by one lane per wave + readfirstlane
//   (per-lane RMWs on one word would serialize 64x).
//   Fast mirrors sit in the dead x-history of the dil==1 layers (0 and 10):
//   WS_NEED unchanged. Compute op order is bit-identical to v2/r1.
// ---------------------------------------------------------------------------

typedef unsigned long long u64;

#define TT 1024
#define WARM 48         // adaptivity warm-up steps
#define FH_MIN 8        // fast hits required to keep fast polling
#define NSPIN_A 4       // fast polls per slow poll during warm-up
#define NSPIN_B 24      // fast polls per slow poll on a proven-fast leg

// byte offsets into d_ws (all 8-B aligned)
#define OFF_PG   0                              // 30*8*256 stamped g-partials
#define OFF_PS   (OFF_PG + 30*8*256*8)          // 30*8*256 stamped s-partials
#define OFF_XV   (OFF_PS + 30*8*256*8)          // 30*256 stamped x values
#define OFF_SB   (OFF_XV + 30*256*8)            // 30*256 stamped running skip
#define OFF_HID  (OFF_SB + 30*256*8)            // 256 stamped head hidden
#define OFF_IDX  (OFF_HID + 256*8)              // 1 stamped sampled index
#define OFF_XH   (OFF_IDX + 64)                 // 30*1024*256 f32 x history
#define WS_NEED  ((size_t)OFF_XH + (size_t)30*1024*256*4)

__device__ __forceinline__ u64 ldp(const u64* p){
    return __hip_atomic_load((u64*)p, __ATOMIC_RELAXED, __HIP_MEMORY_SCOPE_AGENT);
}
__device__ __forceinline__ void stp(u64* p, float v, unsigned stamp){
    union { float f; unsigned u; } c; c.f = v;
    u64 w = ((u64)stamp << 32) | (u64)c.u;
    __hip_atomic_store(p, w, __ATOMIC_RELAXED, __HIP_MEMORY_SCOPE_AGENT);
}
__device__ __forceinline__ void stpu(u64* p, unsigned v, unsigned stamp){
    u64 w = ((u64)stamp << 32) | (u64)v;
    __hip_atomic_store(p, w, __ATOMIC_RELAXED, __HIP_MEMORY_SCOPE_AGENT);
}
__device__ __forceinline__ float pf(u64 w){
    union { unsigned u; float f; } c; c.u = (unsigned)(w & 0xffffffffu); return c.f;
}
__device__ __forceinline__ unsigned pstamp(u64 w){ return (unsigned)(w >> 32); }
__device__ __forceinline__ float ldf(const float* p){
    return __hip_atomic_load((float*)p, __ATOMIC_RELAXED, __HIP_MEMORY_SCOPE_AGENT);
}
__device__ __forceinline__ void stf(float* p, float v){
    __hip_atomic_store(p, v, __ATOMIC_RELAXED, __HIP_MEMORY_SCOPE_AGENT);
}
__device__ __forceinline__ long long rt(){
    return (long long)__builtin_amdgcn_s_memrealtime();
}
// raw barrier: LDS visibility only — does NOT drain vmcnt (in-flight global
// stores keep flying; poll loops' own s_waitcnt retires them each step).
__device__ __forceinline__ void bar_lds(){
    asm volatile("s_waitcnt lgkmcnt(0)\n\ts_barrier" ::: "memory");
}

// ---- fast-path primitives (atomics execute at the XCD's L2) ---------------
__device__ __forceinline__ u64 fld(const u64* p, u64 z){
    return __hip_atomic_fetch_add((u64*)p, z,
                                  __ATOMIC_RELAXED, __HIP_MEMORY_SCOPE_WORKGROUP);
}
__device__ __forceinline__ void fste(u64* p, u64 w){
    (void)__hip_atomic_exchange(p, w, __ATOMIC_RELAXED, __HIP_MEMORY_SCOPE_WORKGROUP);
}
__device__ __forceinline__ u64 pk(float v, unsigned stamp){
    union { float f; unsigned u; } c; c.f = v;
    return ((u64)stamp << 32) | (u64)c.u;
}

__global__ void __launch_bounds__(256, 1)
wavenet_v8(const float* __restrict__ gy,   const float* __restrict__ gemb,
           const float* __restrict__ gcw,  const float* __restrict__ gwvp,
           const float* __restrict__ gwvx, const float* __restrict__ gwo,
           const float* __restrict__ gwob, const float* __restrict__ gwol,
           const float* __restrict__ gwobl,const float* __restrict__ ge1w,
           const float* __restrict__ ge1b, const float* __restrict__ ge2w,
           const float* __restrict__ ge2b, const float* __restrict__ gsmp,
           float one, int* __restrict__ gout, char* __restrict__ ws)
{
    const int b = blockIdx.x, tid = threadIdx.x;
    // XCD-aware role map (performance heuristic only): layer j intended on
    // XCD j>>2 under round-robin dispatch; L28,L29,H1,H2 share XCD7.
    // Correctness never depends on this (dual-path handoff).
    const int xcd = b & 7, kk = b >> 3;
    const int jj = 4*xcd + (kk >> 3);   // 0..29 layer, 30 head, 31 idle
    const int cc = kk & 7;

    if (jj > 30 || (jj == 30 && cc > 2)) return;   // idle blocks

    u64* PG   = (u64*)(ws + OFF_PG);
    u64* PS   = (u64*)(ws + OFF_PS);
    u64* XV   = (u64*)(ws + OFF_XV);
    u64* SB   = (u64*)(ws + OFF_SB);
    u64* HIDP = (u64*)(ws + OFF_HID);
    u64* IDXP = (u64*)(ws + OFF_IDX);
    float* xh = (float*)(ws + OFF_XH);

    // fast mirrors in dead xh space (layers 0 and 10 have dil==1: their xh
    // regions are never read or written by the tap machinery).
    u64* FPG  = (u64*)(ws + OFF_XH);                            // 480 KB
    u64* FPS  = FPG + 30*8*256;                                 // 480 KB
    u64* F2   = (u64*)(ws + OFF_XH + (size_t)10*1024*256*4);
    u64* FXV  = F2;                                             //  60 KB
    u64* FSB  = FXV + 30*256;                                   //  60 KB
    u64* FHID = FSB + 30*256;                                   //   2 KB
    u64* FIDX = FHID + 256;                                     //   8 B

    // opaque zero: compiler cannot prove it is 0 -> fetch_add stays an RMW
    unsigned zr = 0u;
    asm volatile("" : "+v"(zr));
    const u64 z64 = (u64)zr;

    __shared__ float sTap[256];     // tap column (layers) / sX (head)
    __shared__ float sXin[256];     // present x column
    __shared__ float sY[80];
    __shared__ float sZ[32];
    __shared__ float sred[8];
    __shared__ int   sidx[4];

    const long long ddl = rt() + 400000000LL;      // watchdog: wrong, not hung

    // =======================================================================
    if (jj < 30){                                   // ---- layer block ----
        const int j   = jj;
        const int dil = 1 << (j % 10);
        const int q   = tid & 3;                    // 128-col chunk
        const int s   = (tid >> 2) & 15;            // slot in wave
        const int w   = tid >> 6;                   // wave
        // row remap: zw/zf partners 32 lanes apart (shfl_xor 32 gate).
        const int gr  = (s < 8) ? (32*cc + 8*w + s)
                                : (256 + 32*cc + 8*w + (s - 8));

        // --- register-resident weights (×one blocks rematerialization) ---
        const float* rw = (q < 2) ? (gwvp + ((size_t)j*512 + gr)*256 + 128*q)
                                  : (gwvx + ((size_t)j*512 + gr)*256 + 128*(q-2));
        float wv[128];
        #pragma unroll
        for (int i = 0; i < 32; i++){
            const int ci = (i + 2*q) & 31;
            wv[4*i+0] = rw[4*ci+0]*one; wv[4*i+1] = rw[4*ci+1]*one;
            wv[4*i+2] = rw[4*ci+2]*one; wv[4*i+3] = rw[4*ci+3]*one;
        }
        float cw[20];
        {
            const float* cp = gcw + ((size_t)(j*512 + gr))*80 + 20*q;
            #pragma unroll
            for (int i = 0; i < 20; i++) cw[i] = cp[i]*one;
        }
        float wo2[64]; float bres = 0.f, bskip = 0.f;
        if (j < 29){
            const float* w0 = gwo + ((size_t)j*512 + tid)*256 + 32*cc;
            const float* w1 = gwo + ((size_t)j*512 + 256 + tid)*256 + 32*cc;
            #pragma unroll
            for (int i = 0; i < 32; i++){ wo2[i] = w0[i]*one; wo2[32+i] = w1[i]*one; }
            bres  = gwob[j*512 + tid];
            bskip = gwob[j*512 + 256 + tid];
        } else {
            const float* w0 = gwol + (size_t)tid*256 + 32*cc;
            #pragma unroll
            for (int i = 0; i < 32; i++){ wo2[i] = w0[i]*one; wo2[32+i] = 0.f; }
            bskip = gwobl[tid];
        }

        u64* pgj  = PG  + (size_t)j*8*256;
        u64* psj  = PS  + (size_t)j*8*256;
        u64* fpgj = FPG + (size_t)j*8*256;
        u64* fpsj = FPS + (size_t)j*8*256;
        const u64* pgp  = PG  + (size_t)(j > 0 ? j-1 : 0)*8*256 + tid;
        const u64* psp  = PS  + (size_t)(j > 0 ? j-1 : 0)*8*256 + tid;
        const u64* xvp  = XV  + (size_t)(j > 0 ? j-1 : 0)*256 + tid;
        const u64* sbp  = SB  + (size_t)(j >= 2 ? j-1 : 0)*256 + tid;
        const u64* fpgp = FPG + (size_t)(j > 0 ? j-1 : 0)*8*256 + tid;
        const u64* fpsp = FPS + (size_t)(j > 0 ? j-1 : 0)*8*256 + tid;
        const u64* fxvp = FXV + (size_t)(j > 0 ? j-1 : 0)*256 + tid;
        const u64* fsbp = FSB + (size_t)(j >= 2 ? j-1 : 0)*256 + tid;
        float* xhj = xh + (size_t)j*1024*256;
        float xv_prev = 0.f;
        int fh = 0;                                 // steps with a fast hit

        for (int t = 0; t < TT; t++){
            const unsigned stamp = (unsigned)(t + 1);

            // ---- slack phase: stage cond column + dilated tap ----
            if (tid < 80) sY[tid] = gy[tid*TT + t];
            float tapv;
            if (dil == 1) tapv = xv_prev;
            else          tapv = (t >= dil) ? ldf(xhj + (size_t)(t-dil)*256 + tid) : 0.f;
            sTap[tid] = tapv;
            bar_lds();

            float acc = 0.f;
            #pragma unroll
            for (int i = 0; i < 20; i++) acc = fmaf(cw[i], sY[20*q + i], acc);
            if (q < 2){                              // WV_past half: pre-poll
                const float4* x4 = (const float4*)(sTap + 128*q);
                #pragma unroll
                for (int i = 0; i < 32; i++){
                    const int ci = (i + 2*q) & 31;
                    float4 v = x4[ci];
                    acc = fmaf(wv[4*i+0], v.x, acc); acc = fmaf(wv[4*i+1], v.y, acc);
                    acc = fmaf(wv[4*i+2], v.z, acc); acc = fmaf(wv[4*i+3], v.w, acc);
                }
            }

            // ---- poll stamped records; payload arrives with the detect ----
            float xv;
            if (j == 0){
                if (t == 0){
                    xv = gemb[127*256 + tid];
                } else {
                    u64 wIdx = 0; bool got = false;
                    const bool tryfast = (t < WARM) || (fh >= FH_MIN);
                    const int  nspin   = (t < WARM) ? NSPIN_A : NSPIN_B;
                    do {
                        if (tryfast){
                            for (int k = 0; k < nspin && !got; k++){
                                u64 v = 0;
                                if ((tid & 63) == 0) v = fld(FIDX, z64);
                                unsigned lo = __builtin_amdgcn_readfirstlane(
                                                  (unsigned)(v & 0xffffffffu));
                                unsigned hi = __builtin_amdgcn_readfirstlane(
                                                  (unsigned)(v >> 32));
                                wIdx = ((u64)hi << 32) | lo;
                                got = (pstamp(wIdx) == (unsigned)t);
                            }
                            if (got){ fh++; break; }
                        }
                        wIdx = ldp(IDXP);                   // v2 slow check
                        got = (pstamp(wIdx) == (unsigned)t);
                    } while (!got && rt() <= ddl);
                    const int idx = (int)(wIdx & 0xffffffffu) & 255;
                    xv = gemb[idx*256 + tid];        // emb is read-only: cached
                }
            } else {
                u64 gwv[8]; u64 xvw = 0; u64 swv[8] = {0,0,0,0,0,0,0,0}; u64 sbw = 0;
                bool got = false;
                const bool tryfast = (t < WARM) || (fh >= FH_MIN);
                const int  nspin   = (t < WARM) ? NSPIN_A : NSPIN_B;
                do {
                    if (tryfast){                    // ---- fast: L2 atomics ----
                        for (int k = 0; k < nspin && !got; k++){
                            bool ok;
                            #pragma unroll
                            for (int c2 = 0; c2 < 8; c2++)
                                gwv[c2] = fld(fpgp + c2*256, z64);
                            xvw = fld(fxvp, z64);
                            ok = (pstamp(xvw) == stamp);
                            #pragma unroll
                            for (int c2 = 0; c2 < 8; c2++)
                                ok &= (pstamp(gwv[c2]) == stamp);
                            if (cc == 0){
                                #pragma unroll
                                for (int c2 = 0; c2 < 8; c2++){
                                    swv[c2] = fld(fpsp + c2*256, z64);
                                    ok &= (pstamp(swv[c2]) == stamp);
                                }
                                if (j >= 2){ sbw = fld(fsbp, z64);
                                             ok &= (pstamp(sbw) == stamp); }
                            }
                            got = (__all(ok) != 0);
                        }
                        if (got){ fh++; break; }
                    }
                    {                                // ---- slow: v2 agent poll ----
                        bool ok;
                        #pragma unroll
                        for (int c2 = 0; c2 < 8; c2++) gwv[c2] = ldp(pgp + c2*256);
                        xvw = ldp(xvp);
                        ok = (pstamp(xvw) == stamp);
                        #pragma unroll
                        for (int c2 = 0; c2 < 8; c2++)
                            ok &= (pstamp(gwv[c2]) == stamp);
                        if (cc == 0){
                            #pragma unroll
                            for (int c2 = 0; c2 < 8; c2++){
                                swv[c2] = ldp(psp + c2*256);
                                ok &= (pstamp(swv[c2]) == stamp);
                            }
                            if (j >= 2){ sbw = ldp(sbp);
                                         ok &= (pstamp(sbw) == stamp); }
                        }
                        got = (__all(ok) != 0);
                    }
                } while (!got && rt() <= ddl);
                xv = pf(xvw);                        // same gather order as r1
                #pragma unroll
                for (int c2 = 0; c2 < 8; c2++) xv += pf(gwv[c2]);
                if (cc == 0){                        // deterministic skip chain
                    float sv = (j >= 2) ? pf(sbw) : 0.f;
                    #pragma unroll
                    for (int c2 = 0; c2 < 8; c2++) sv += pf(swv[c2]);
                    fste(FSB + (size_t)j*256 + tid, pk(sv, stamp));   // fast first
                    stp(SB + (size_t)j*256 + tid, sv, stamp);
                }
            }
            xv_prev = xv;
            sXin[tid] = xv;
            if (cc == 0){
                fste(FXV + (size_t)j*256 + tid, pk(xv, stamp));
                stp(XV + (size_t)j*256 + tid, xv, stamp);   // x_j for layer j+1
                if (dil > 1) stf(xhj + (size_t)t*256 + tid, xv); // own future tap
            }
            bar_lds();

            if (q >= 2){                             // WV_present half: post-poll
                const float4* x4 = (const float4*)(sXin + 128*(q-2));
                #pragma unroll
                for (int i = 0; i < 32; i++){
                    const int ci = (i + 2*q) & 31;
                    float4 v = x4[ci];
                    acc = fmaf(wv[4*i+0], v.x, acc); acc = fmaf(wv[4*i+1], v.y, acc);
                    acc = fmaf(wv[4*i+2], v.z, acc); acc = fmaf(wv[4*i+3], v.w, acc);
                }
            }
            acc += __shfl_xor(acc, 1, 64);
            acc += __shfl_xor(acc, 2, 64);
            const float hpart = __shfl_xor(acc, 32, 64);   // zf partner
            if (q == 0 && s < 8)
                sZ[8*w + s] = tanhf(acc) * (1.f/(1.f + expf(-hpart)));
            bar_lds();

            // ---- rank-32 column partial of W_o @ z ----
            float g = 0.f, sk = 0.f;
            const float4* z4 = (const float4*)sZ;
            #pragma unroll
            for (int i = 0; i < 8; i++){
                float4 v = z4[i];
                g  = fmaf(wo2[4*i+0], v.x, g);  g  = fmaf(wo2[4*i+1], v.y, g);
                g  = fmaf(wo2[4*i+2], v.z, g);  g  = fmaf(wo2[4*i+3], v.w, g);
                sk = fmaf(wo2[32+4*i+0], v.x, sk); sk = fmaf(wo2[32+4*i+1], v.y, sk);
                sk = fmaf(wo2[32+4*i+2], v.z, sk); sk = fmaf(wo2[32+4*i+3], v.w, sk);
            }
            if (j < 29){
                if (cc == 0){ g += bres; sk += bskip; }     // bias folded once
                fste(fpgj + cc*256 + tid, pk(g,  stamp));   // fast first
                fste(fpsj + cc*256 + tid, pk(sk, stamp));
                stp(pgj + cc*256 + tid, g,  stamp);
                stp(psj + cc*256 + tid, sk, stamp);
            } else {
                if (cc == 0) g += bskip;                    // last layer: skip only
                fste(fpsj + cc*256 + tid, pk(g, stamp));
                stp(psj + cc*256 + tid, g, stamp);
            }
            // no drain, no flag: stores self-describe via their stamps
        }
        return;
    }

    // =======================================================================
    if (jj == 30 && cc < 2){                        // ---- H1: end1 ----
        const int half = cc;
        const int r  = 128*half + (tid >> 1);
        const int hc = tid & 1;
        float e1[128];
        {
            const float* wp = ge1w + (size_t)r*256 + 128*hc;
            #pragma unroll
            for (int i = 0; i < 128; i++) e1[i] = wp[i]*one;
        }
        const float b1 = ge1b[r];
        const u64* psp  = PS  + (size_t)29*8*256 + tid;
        const u64* sbp  = SB  + (size_t)29*256 + tid;
        const u64* fpsp = FPS + (size_t)29*8*256 + tid;
        const u64* fsbp = FSB + (size_t)29*256 + tid;
        int fh = 0;

        for (int t = 0; t < TT; t++){
            const unsigned stamp = (unsigned)(t + 1);
            u64 swv[8]; u64 sbw = 0; bool got = false;
            const bool tryfast = (t < WARM) || (fh >= FH_MIN);
            const int  nspin   = (t < WARM) ? NSPIN_A : NSPIN_B;
            do {
                if (tryfast){
                    for (int k = 0; k < nspin && !got; k++){
                        bool ok;
                        #pragma unroll
                        for (int c2 = 0; c2 < 8; c2++)
                            swv[c2] = fld(fpsp + c2*256, z64);
                        sbw = fld(fsbp, z64);
                        ok = (pstamp(sbw) == stamp);
                        #pragma unroll
                        for (int c2 = 0; c2 < 8; c2++)
                            ok &= (pstamp(swv[c2]) == stamp);
                        got = (__all(ok) != 0);
                    }
                    if (got){ fh++; break; }
                }
                {   // v2 slow check
                    bool ok;
                    #pragma unroll
                    for (int c2 = 0; c2 < 8; c2++) swv[c2] = ldp(psp + c2*256);
                    sbw = ldp(sbp);
                    ok = (pstamp(sbw) == stamp);
                    #pragma unroll
                    for (int c2 = 0; c2 < 8; c2++)
                        ok &= (pstamp(swv[c2]) == stamp);
                    got = (__all(ok) != 0);
                }
            } while (!got && rt() <= ddl);
            float sk = pf(sbw);
            #pragma unroll
            for (int c2 = 0; c2 < 8; c2++) sk += pf(swv[c2]);
            sTap[tid] = fmaxf(sk, 0.f);             // relu(skip)
            bar_lds();
            float a = 0.f;
            const float4* p4 = (const float4*)(sTap + 128*hc);
            #pragma unroll
            for (int i = 0; i < 32; i++){
                float4 v = p4[i];
                a = fmaf(e1[4*i+0], v.x, a); a = fmaf(e1[4*i+1], v.y, a);
                a = fmaf(e1[4*i+2], v.z, a); a = fmaf(e1[4*i+3], v.w, a);
            }
            a += __shfl_xor(a, 1, 64);
            if (hc == 0){
                const float hv = fmaxf(a + b1, 0.f);
                fste(FHID + r, pk(hv, stamp));
                stp(HIDP + r, hv, stamp);
            }
            bar_lds();                               // sTap reuse guard
        }
        return;
    }

    // =======================================================================
    {                                               // ---- H2: end2 + sample ----
        float e2[256];
        {
            const float* wp = ge2w + (size_t)tid*256;
            #pragma unroll
            for (int i = 0; i < 256; i++) e2[i] = wp[i]*one;
        }
        const float b2 = ge2b[tid];
        const int w = tid >> 6, lane = tid & 63;
        int fh = 0;

        for (int t = 0; t < TT; t++){
            const unsigned stamp = (unsigned)(t + 1);
            u64 hw = 0; bool got = false;
            const bool tryfast = (t < WARM) || (fh >= FH_MIN);
            const int  nspin   = (t < WARM) ? NSPIN_A : NSPIN_B;
            do {
                if (tryfast){
                    for (int k = 0; k < nspin && !got; k++){
                        hw = fld(FHID + tid, z64);
                        got = (__all(pstamp(hw) == stamp) != 0);
                    }
                    if (got){ fh++; break; }
                }
                hw = ldp(HIDP + tid);                // v2 slow check
                got = (__all(pstamp(hw) == stamp) != 0);
            } while (!got && rt() <= ddl);
            sTap[tid] = pf(hw);
            bar_lds();
            float a = b2;
            const float4* p4 = (const float4*)sTap;
            #pragma unroll
            for (int i = 0; i < 64; i++){
                float4 v = p4[i];
                a = fmaf(e2[4*i+0], v.x, a); a = fmaf(e2[4*i+1], v.y, a);
                a = fmaf(e2[4*i+2], v.z, a); a = fmaf(e2[4*i+3], v.w, a);
            }
            // softmax + cumsum + first cum > u (identical op order to round 1)
            float m = a;
            #pragma unroll
            for (int off = 32; off > 0; off >>= 1) m = fmaxf(m, __shfl_xor(m, off, 64));
            if (lane == 0) sred[w] = m;
            bar_lds();
            m = fmaxf(fmaxf(sred[0], sred[1]), fmaxf(sred[2], sred[3]));
            float pe = expf(a - m);
            float ssum = pe;
            #pragma unroll
            for (int off = 32; off > 0; off >>= 1) ssum += __shfl_xor(ssum, off, 64);
            if (lane == 0) sred[4 + w] = ssum;
            bar_lds();
            const float S = sred[4] + sred[5] + sred[6] + sred[7];
            float cum = pe / S;
            #pragma unroll
            for (int off = 1; off < 64; off <<= 1){
                float vv = __shfl_up(cum, off, 64);
                if (lane >= off) cum += vv;
            }
            if (lane == 63) sred[w] = cum;
            bar_lds();
            float base = 0.f;
            if (w > 0) base += sred[0];
            if (w > 1) base += sred[1];
            if (w > 2) base += sred[2];
            cum += base;
            const float u = gsmp[t];
            unsigned long long bal = __ballot(cum > u);
            int cand = bal ? (w*64 + __ffsll((long long)bal) - 1) : (1 << 30);
            if (lane == 0) sidx[w] = cand;
            bar_lds();
            int idx = min(min(sidx[0], sidx[1]), min(sidx[2], sidx[3]));
            if (idx > 255) idx = 0;
            if (tid == 0){
                gout[t] = idx;
                fste(FIDX, ((u64)stamp << 32) | (u64)(unsigned)idx);
                stpu(IDXP, (unsigned)idx, stamp);    // feedback to layer 0
            }
            bar_lds();                               // sred/sidx reuse guard
        }
        return;
    }
}

__global__ void ws_too_small_kernel(int* out, int n){
    int i = blockIdx.x*256 + threadIdx.x;
    if (i < n) out[i] = 0;
}

extern "C" void kernel_launch(void* const* d_in, const int* in_sizes, int n_in,
                              void* d_out, int out_size, void* d_ws, size_t ws_size,
                              hipStream_t stream){
    (void)in_sizes; (void)n_in;
    if (ws_size < WS_NEED){
        hipLaunchKernelGGL(ws_too_small_kernel, dim3(4), dim3(256), 0, stream,
                           (int*)d_out, out_size);
        return;
    }
    hipLaunchKernelGGL(wavenet_v8, dim3(256), dim3(256), 0, stream,
                       (const float*)d_in[0],  (const float*)d_in[1],
                       (const float*)d_in[2],  (const float*)d_in[3],
                       (const float*)d_in[4],  (const float*)d_in[5],
                       (const float*)d_in[6],  (const float*)d_in[7],
                       (const float*)d_in[8],  (const float*)d_in[9],
                       (const float*)d_in[10], (const float*)d_in[11],
                       (const float*)d_in[12], (const float*)d_in[13],
                       1.0f, (int*)d_out, (char*)d_ws);
}

// Round 7
// 109077.307 us; speedup vs baseline: 6.1398x; 6.1398x over previous
//
#include <hip/hip_runtime.h>
#include <stdint.h>

// ---------------------------------------------------------------------------
// FastWaveNet autoregressive sampler v9 — persistent pipeline with
// self-validating stamped 64-bit records (v2 structure restored).
// Rounds 3-6 hardware-falsified every "fast same-XCD L2 handoff" mechanism:
//   v3: poll-traffic throttling -> dur unchanged (congestion falsified)
//   v7: plain-store + sc0-load  -> fast path never hit
//   v8: workgroup-scope atomics -> RMWs execute at the MEMORY-SIDE coherence
//       point (1 TB of HBM writes), not in the XCD L2
// => the agent-scope hop (~3.2us) is the fabric latency floor; 33 serial
//    legs x 1024 steps = ~108 ms. Weight distribution (46 MB in registers)
//    makes the hop count structurally minimal.
// v9 = v2 + ONE micro-change on the critical path: cc==0 consumers split
// their 18-record poll into {9 x-critical records -> publish XV} then
// {9 skip records -> publish SB}. Same loads, same summation order ->
// bit-identical output; halves cc0's poll-iteration length (finer detect
// granularity on the x-chain records).
// ---------------------------------------------------------------------------

typedef unsigned long long u64;

#define TT 1024

// byte offsets into d_ws (all 8-B aligned)
#define OFF_PG   0                              // 30*8*256 stamped g-partials
#define OFF_PS   (OFF_PG + 30*8*256*8)          // 30*8*256 stamped s-partials
#define OFF_XV   (OFF_PS + 30*8*256*8)          // 30*256 stamped x values
#define OFF_SB   (OFF_XV + 30*256*8)            // 30*256 stamped running skip
#define OFF_HID  (OFF_SB + 30*256*8)            // 256 stamped head hidden
#define OFF_IDX  (OFF_HID + 256*8)              // 1 stamped sampled index
#define OFF_XH   (OFF_IDX + 64)                 // 30*1024*256 f32 x history
#define WS_NEED  ((size_t)OFF_XH + (size_t)30*1024*256*4)

__device__ __forceinline__ u64 ldp(const u64* p){
    return __hip_atomic_load((u64*)p, __ATOMIC_RELAXED, __HIP_MEMORY_SCOPE_AGENT);
}
__device__ __forceinline__ void stp(u64* p, float v, unsigned stamp){
    union { float f; unsigned u; } c; c.f = v;
    u64 w = ((u64)stamp << 32) | (u64)c.u;
    __hip_atomic_store(p, w, __ATOMIC_RELAXED, __HIP_MEMORY_SCOPE_AGENT);
}
__device__ __forceinline__ void stpu(u64* p, unsigned v, unsigned stamp){
    u64 w = ((u64)stamp << 32) | (u64)v;
    __hip_atomic_store(p, w, __ATOMIC_RELAXED, __HIP_MEMORY_SCOPE_AGENT);
}
__device__ __forceinline__ float pf(u64 w){
    union { unsigned u; float f; } c; c.u = (unsigned)(w & 0xffffffffu); return c.f;
}
__device__ __forceinline__ unsigned pstamp(u64 w){ return (unsigned)(w >> 32); }
__device__ __forceinline__ float ldf(const float* p){
    return __hip_atomic_load((float*)p, __ATOMIC_RELAXED, __HIP_MEMORY_SCOPE_AGENT);
}
__device__ __forceinline__ void stf(float* p, float v){
    __hip_atomic_store(p, v, __ATOMIC_RELAXED, __HIP_MEMORY_SCOPE_AGENT);
}
__device__ __forceinline__ long long rt(){
    return (long long)__builtin_amdgcn_s_memrealtime();
}
// raw barrier: LDS visibility only — does NOT drain vmcnt (in-flight global
// stores keep flying; poll loops' own s_waitcnt retires them each step).
__device__ __forceinline__ void bar_lds(){
    asm volatile("s_waitcnt lgkmcnt(0)\n\ts_barrier" ::: "memory");
}

__global__ void __launch_bounds__(256, 1)
wavenet_v9(const float* __restrict__ gy,   const float* __restrict__ gemb,
           const float* __restrict__ gcw,  const float* __restrict__ gwvp,
           const float* __restrict__ gwvx, const float* __restrict__ gwo,
           const float* __restrict__ gwob, const float* __restrict__ gwol,
           const float* __restrict__ gwobl,const float* __restrict__ ge1w,
           const float* __restrict__ ge1b, const float* __restrict__ ge2w,
           const float* __restrict__ ge2b, const float* __restrict__ gsmp,
           float one, int* __restrict__ gout, char* __restrict__ ws)
{
    const int b = blockIdx.x, tid = threadIdx.x;
    // XCD-aware role map (performance heuristic only): layer j on XCD j>>2.
    const int xcd = b & 7, kk = b >> 3;
    const int jj = 4*xcd + (kk >> 3);   // 0..29 layer, 30 head, 31 idle
    const int cc = kk & 7;

    if (jj > 30 || (jj == 30 && cc > 2)) return;   // idle blocks

    u64* PG   = (u64*)(ws + OFF_PG);
    u64* PS   = (u64*)(ws + OFF_PS);
    u64* XV   = (u64*)(ws + OFF_XV);
    u64* SB   = (u64*)(ws + OFF_SB);
    u64* HIDP = (u64*)(ws + OFF_HID);
    u64* IDXP = (u64*)(ws + OFF_IDX);
    float* xh = (float*)(ws + OFF_XH);

    __shared__ float sTap[256];     // tap column (layers) / sX (head)
    __shared__ float sXin[256];     // present x column
    __shared__ float sY[80];
    __shared__ float sZ[32];
    __shared__ float sred[8];
    __shared__ int   sidx[4];

    const long long ddl = rt() + 400000000LL;      // watchdog: wrong, not hung

    // =======================================================================
    if (jj < 30){                                   // ---- layer block ----
        const int j   = jj;
        const int dil = 1 << (j % 10);
        const int q   = tid & 3;                    // 128-col chunk
        const int s   = (tid >> 2) & 15;            // slot in wave
        const int w   = tid >> 6;                   // wave
        // row remap: zw/zf partners 32 lanes apart (shfl_xor 32 gate).
        const int gr  = (s < 8) ? (32*cc + 8*w + s)
                                : (256 + 32*cc + 8*w + (s - 8));

        // --- register-resident weights (×one blocks rematerialization) ---
        const float* rw = (q < 2) ? (gwvp + ((size_t)j*512 + gr)*256 + 128*q)
                                  : (gwvx + ((size_t)j*512 + gr)*256 + 128*(q-2));
        float wv[128];
        #pragma unroll
        for (int i = 0; i < 32; i++){
            const int ci = (i + 2*q) & 31;
            wv[4*i+0] = rw[4*ci+0]*one; wv[4*i+1] = rw[4*ci+1]*one;
            wv[4*i+2] = rw[4*ci+2]*one; wv[4*i+3] = rw[4*ci+3]*one;
        }
        float cw[20];
        {
            const float* cp = gcw + ((size_t)(j*512 + gr))*80 + 20*q;
            #pragma unroll
            for (int i = 0; i < 20; i++) cw[i] = cp[i]*one;
        }
        float wo2[64]; float bres = 0.f, bskip = 0.f;
        if (j < 29){
            const float* w0 = gwo + ((size_t)j*512 + tid)*256 + 32*cc;
            const float* w1 = gwo + ((size_t)j*512 + 256 + tid)*256 + 32*cc;
            #pragma unroll
            for (int i = 0; i < 32; i++){ wo2[i] = w0[i]*one; wo2[32+i] = w1[i]*one; }
            bres  = gwob[j*512 + tid];
            bskip = gwob[j*512 + 256 + tid];
        } else {
            const float* w0 = gwol + (size_t)tid*256 + 32*cc;
            #pragma unroll
            for (int i = 0; i < 32; i++){ wo2[i] = w0[i]*one; wo2[32+i] = 0.f; }
            bskip = gwobl[tid];
        }

        u64* pgj = PG + (size_t)j*8*256;
        u64* psj = PS + (size_t)j*8*256;
        const u64* pgp = PG + (size_t)(j > 0 ? j-1 : 0)*8*256 + tid;
        const u64* psp = PS + (size_t)(j > 0 ? j-1 : 0)*8*256 + tid;
        const u64* xvp = XV + (size_t)(j > 0 ? j-1 : 0)*256 + tid;
        const u64* sbp = SB + (size_t)(j >= 2 ? j-1 : 0)*256 + tid;
        float* xhj = xh + (size_t)j*1024*256;
        float xv_prev = 0.f;

        for (int t = 0; t < TT; t++){
            const unsigned stamp = (unsigned)(t + 1);

            // ---- slack phase: stage cond column + dilated tap ----
            if (tid < 80) sY[tid] = gy[tid*TT + t];
            float tapv;
            if (dil == 1) tapv = xv_prev;
            else          tapv = (t >= dil) ? ldf(xhj + (size_t)(t-dil)*256 + tid) : 0.f;
            sTap[tid] = tapv;
            bar_lds();

            float acc = 0.f;
            #pragma unroll
            for (int i = 0; i < 20; i++) acc = fmaf(cw[i], sY[20*q + i], acc);
            if (q < 2){                              // WV_past half: pre-poll
                const float4* x4 = (const float4*)(sTap + 128*q);
                #pragma unroll
                for (int i = 0; i < 32; i++){
                    const int ci = (i + 2*q) & 31;
                    float4 v = x4[ci];
                    acc = fmaf(wv[4*i+0], v.x, acc); acc = fmaf(wv[4*i+1], v.y, acc);
                    acc = fmaf(wv[4*i+2], v.z, acc); acc = fmaf(wv[4*i+3], v.w, acc);
                }
            }

            // ---- poll stamped records; payload arrives with the detect ----
            float xv;
            if (j == 0){
                if (t == 0){
                    xv = gemb[127*256 + tid];
                } else {
                    u64 wIdx; int c = 0;
                    do {
                        wIdx = ldp(IDXP);
                        if (((++c) & 255) == 0 && rt() > ddl) break;
                    } while (pstamp(wIdx) != (unsigned)t);
                    const int idx = (int)(wIdx & 0xffffffffu) & 255;
                    xv = gemb[idx*256 + tid];        // emb is read-only: cached
                }
                xv_prev = xv;
                sXin[tid] = xv;
                if (cc == 0) stp(XV + (size_t)j*256 + tid, xv, stamp);
            } else {
                // -- poll the 9 x-critical records only (short iteration) --
                u64 gwv[8]; u64 xvw = 0;
                bool fresh; int c = 0;
                do {
                    #pragma unroll
                    for (int c2 = 0; c2 < 8; c2++) gwv[c2] = ldp(pgp + c2*256);
                    xvw = ldp(xvp);
                    bool ok = (pstamp(xvw) == stamp);
                    #pragma unroll
                    for (int c2 = 0; c2 < 8; c2++) ok &= (pstamp(gwv[c2]) == stamp);
                    fresh = ok;
                    if (((++c) & 255) == 0 && rt() > ddl) break;
                } while (!fresh);
                xv = pf(xvw);                        // same gather order as r1
                #pragma unroll
                for (int c2 = 0; c2 < 8; c2++) xv += pf(gwv[c2]);
                xv_prev = xv;
                sXin[tid] = xv;
                if (cc == 0){
                    // publish x_j immediately (consumed by layer j+1)
                    stp(XV + (size_t)j*256 + tid, xv, stamp);
                    if (dil > 1) stf(xhj + (size_t)t*256 + tid, xv);
                    // -- now await skip records (usually already fresh) --
                    u64 swv[8]; u64 sbw = 0; int c3 = 0; bool fr2;
                    do {
                        #pragma unroll
                        for (int c2 = 0; c2 < 8; c2++) swv[c2] = ldp(psp + c2*256);
                        bool ok = true;
                        #pragma unroll
                        for (int c2 = 0; c2 < 8; c2++) ok &= (pstamp(swv[c2]) == stamp);
                        if (j >= 2){ sbw = ldp(sbp); ok &= (pstamp(sbw) == stamp); }
                        fr2 = ok;
                        if (((++c3) & 255) == 0 && rt() > ddl) break;
                    } while (!fr2);
                    float sv = (j >= 2) ? pf(sbw) : 0.f;   // same sum order as v2
                    #pragma unroll
                    for (int c2 = 0; c2 < 8; c2++) sv += pf(swv[c2]);
                    stp(SB + (size_t)j*256 + tid, sv, stamp);
                }
            }
            bar_lds();

            if (q >= 2){                             // WV_present half: post-poll
                const float4* x4 = (const float4*)(sXin + 128*(q-2));
                #pragma unroll
                for (int i = 0; i < 32; i++){
                    const int ci = (i + 2*q) & 31;
                    float4 v = x4[ci];
                    acc = fmaf(wv[4*i+0], v.x, acc); acc = fmaf(wv[4*i+1], v.y, acc);
                    acc = fmaf(wv[4*i+2], v.z, acc); acc = fmaf(wv[4*i+3], v.w, acc);
                }
            }
            acc += __shfl_xor(acc, 1, 64);
            acc += __shfl_xor(acc, 2, 64);
            const float hpart = __shfl_xor(acc, 32, 64);   // zf partner
            if (q == 0 && s < 8)
                sZ[8*w + s] = tanhf(acc) * (1.f/(1.f + expf(-hpart)));
            bar_lds();

            // ---- rank-32 column partial of W_o @ z ----
            float g = 0.f, sk = 0.f;
            const float4* z4 = (const float4*)sZ;
            #pragma unroll
            for (int i = 0; i < 8; i++){
                float4 v = z4[i];
                g  = fmaf(wo2[4*i+0], v.x, g);  g  = fmaf(wo2[4*i+1], v.y, g);
                g  = fmaf(wo2[4*i+2], v.z, g);  g  = fmaf(wo2[4*i+3], v.w, g);
                sk = fmaf(wo2[32+4*i+0], v.x, sk); sk = fmaf(wo2[32+4*i+1], v.y, sk);
                sk = fmaf(wo2[32+4*i+2], v.z, sk); sk = fmaf(wo2[32+4*i+3], v.w, sk);
            }
            if (j < 29){
                if (cc == 0){ g += bres; sk += bskip; }     // bias folded once
                stp(pgj + cc*256 + tid, g,  stamp);
                stp(psj + cc*256 + tid, sk, stamp);
            } else {
                if (cc == 0) g += bskip;                    // last layer: skip only
                stp(psj + cc*256 + tid, g, stamp);
            }
            // no drain, no flag: stores self-describe via their stamps
        }
        return;
    }

    // =======================================================================
    if (jj == 30 && cc < 2){                        // ---- H1: end1 ----
        const int half = cc;
        const int r  = 128*half + (tid >> 1);
        const int hc = tid & 1;
        float e1[128];
        {
            const float* wp = ge1w + (size_t)r*256 + 128*hc;
            #pragma unroll
            for (int i = 0; i < 128; i++) e1[i] = wp[i]*one;
        }
        const float b1 = ge1b[r];
        const u64* psp = PS + (size_t)29*8*256 + tid;
        const u64* sbp = SB + (size_t)29*256 + tid;

        for (int t = 0; t < TT; t++){
            const unsigned stamp = (unsigned)(t + 1);
            u64 swv[8]; u64 sbw = 0; bool fresh; int c = 0;
            do {
                #pragma unroll
                for (int c2 = 0; c2 < 8; c2++) swv[c2] = ldp(psp + c2*256);
                sbw = ldp(sbp);
                bool ok = (pstamp(sbw) == stamp);
                #pragma unroll
                for (int c2 = 0; c2 < 8; c2++) ok &= (pstamp(swv[c2]) == stamp);
                fresh = ok;
                if (((++c) & 255) == 0 && rt() > ddl) break;
            } while (!fresh);
            float sk = pf(sbw);
            #pragma unroll
            for (int c2 = 0; c2 < 8; c2++) sk += pf(swv[c2]);
            sTap[tid] = fmaxf(sk, 0.f);             // relu(skip)
            bar_lds();
            float a = 0.f;
            const float4* p4 = (const float4*)(sTap + 128*hc);
            #pragma unroll
            for (int i = 0; i < 32; i++){
                float4 v = p4[i];
                a = fmaf(e1[4*i+0], v.x, a); a = fmaf(e1[4*i+1], v.y, a);
                a = fmaf(e1[4*i+2], v.z, a); a = fmaf(e1[4*i+3], v.w, a);
            }
            a += __shfl_xor(a, 1, 64);
            if (hc == 0) stp(HIDP + r, fmaxf(a + b1, 0.f), stamp);
            bar_lds();                               // sTap reuse guard
        }
        return;
    }

    // =======================================================================
    {                                               // ---- H2: end2 + sample ----
        float e2[256];
        {
            const float* wp = ge2w + (size_t)tid*256;
            #pragma unroll
            for (int i = 0; i < 256; i++) e2[i] = wp[i]*one;
        }
        const float b2 = ge2b[tid];
        const int w = tid >> 6, lane = tid & 63;

        for (int t = 0; t < TT; t++){
            const unsigned stamp = (unsigned)(t + 1);
            u64 hw; int c = 0;
            do {
                hw = ldp(HIDP + tid);
                if (((++c) & 255) == 0 && rt() > ddl) break;
            } while (pstamp(hw) != stamp);
            sTap[tid] = pf(hw);
            bar_lds();
            float a = b2;
            const float4* p4 = (const float4*)sTap;
            #pragma unroll
            for (int i = 0; i < 64; i++){
                float4 v = p4[i];
                a = fmaf(e2[4*i+0], v.x, a); a = fmaf(e2[4*i+1], v.y, a);
                a = fmaf(e2[4*i+2], v.z, a); a = fmaf(e2[4*i+3], v.w, a);
            }
            // softmax + cumsum + first cum > u (identical op order to round 1)
            float m = a;
            #pragma unroll
            for (int off = 32; off > 0; off >>= 1) m = fmaxf(m, __shfl_xor(m, off, 64));
            if (lane == 0) sred[w] = m;
            bar_lds();
            m = fmaxf(fmaxf(sred[0], sred[1]), fmaxf(sred[2], sred[3]));
            float pe = expf(a - m);
            float ssum = pe;
            #pragma unroll
            for (int off = 32; off > 0; off >>= 1) ssum += __shfl_xor(ssum, off, 64);
            if (lane == 0) sred[4 + w] = ssum;
            bar_lds();
            const float S = sred[4] + sred[5] + sred[6] + sred[7];
            float cum = pe / S;
            #pragma unroll
            for (int off = 1; off < 64; off <<= 1){
                float vv = __shfl_up(cum, off, 64);
                if (lane >= off) cum += vv;
            }
            if (lane == 63) sred[w] = cum;
            bar_lds();
            float base = 0.f;
            if (w > 0) base += sred[0];
            if (w > 1) base += sred[1];
            if (w > 2) base += sred[2];
            cum += base;
            const float u = gsmp[t];
            unsigned long long bal = __ballot(cum > u);
            int cand = bal ? (w*64 + __ffsll((long long)bal) - 1) : (1 << 30);
            if (lane == 0) sidx[w] = cand;
            bar_lds();
            int idx = min(min(sidx[0], sidx[1]), min(sidx[2], sidx[3]));
            if (idx > 255) idx = 0;
            if (tid == 0){
                gout[t] = idx;
                stpu(IDXP, (unsigned)idx, stamp);    // feedback to layer 0
            }
            bar_lds();                               // sred/sidx reuse guard
        }
        return;
    }
}

__global__ void ws_too_small_kernel(int* out, int n){
    int i = blockIdx.x*256 + threadIdx.x;
    if (i < n) out[i] = 0;
}

extern "C" void kernel_launch(void* const* d_in, const int* in_sizes, int n_in,
                              void* d_out, int out_size, void* d_ws, size_t ws_size,
                              hipStream_t stream){
    (void)in_sizes; (void)n_in;
    if (ws_size < WS_NEED){
        hipLaunchKernelGGL(ws_too_small_kernel, dim3(4), dim3(256), 0, stream,
                           (int*)d_out, out_size);
        return;
    }
    hipLaunchKernelGGL(wavenet_v9, dim3(256), dim3(256), 0, stream,
                       (const float*)d_in[0],  (const float*)d_in[1],
                       (const float*)d_in[2],  (const float*)d_in[3],
                       (const float*)d_in[4],  (const float*)d_in[5],
                       (const float*)d_in[6],  (const float*)d_in[7],
                       (const float*)d_in[8],  (const float*)d_in[9],
                       (const float*)d_in[10], (const float*)d_in[11],
                       (const float*)d_in[12], (const float*)d_in[13],
                       1.0f, (int*)d_out, (char*)d_ws);
}